// Round 1
// baseline (465.930 us; speedup 1.0000x reference)
//
#include <hip/hip_runtime.h>

typedef _Float16 half8 __attribute__((ext_vector_type(8)));
typedef float floatx4 __attribute__((ext_vector_type(4)));

#define NTOK 16384
#define DM   4096
#define NE   128
#define MT   32                  // tokens per block
#define BK   64                  // k per iter
#define NITER (DM / BK)          // 64 (full K, no split)
#define NBLK (NTOK / MT)         // 512
#define TEMP 0.3f
#define CSTRIDE 528
#define ABUF (8 * CSTRIDE)
#define BUFSZ (2 * ABUF)
#define LSTRIDE 33               // 128x33 floats = 16896 B = 2*BUFSZ exactly

// ---------------- prep: pack wg into MFMA b-fragment order, f16x2 split ----------------
__global__ void pack_b_kernel(const float* __restrict__ wg, _Float16* __restrict__ Bp) {
    int gtid = blockIdx.x * blockDim.x + threadIdx.x;
    int l  = gtid & 63;
    int tg = gtid >> 6;
    int g  = tg & 7;
    int kc = tg >> 3;
    const float* src = wg + (size_t)(g * 16 + (l & 15)) * DM + kc * 32 + (l >> 4) * 8;
    float4 v0 = *(const float4*)src;
    float4 v1 = *(const float4*)(src + 4);
    float f[8] = {v0.x, v0.y, v0.z, v0.w, v1.x, v1.y, v1.z, v1.w};
    half8 h1, h2;
#pragma unroll
    for (int j = 0; j < 8; j++) {
        h1[j] = (_Float16)f[j];
        h2[j] = (_Float16)((f[j] - (float)h1[j]) * 2048.0f);
    }
    char* dst = (char*)Bp + (size_t)tg * 2048 + l * 16;
    *(half8*)dst = h1;
    *(half8*)(dst + 1024) = h2;
}

// ---------------- fused GEMM + top-2 + softmax + me/ce ----------------
__device__ __forceinline__ void stage_write(unsigned char* base, unsigned off,
                                            float4 v0, float4 v1) {
    float f[8] = {v0.x, v0.y, v0.z, v0.w, v1.x, v1.y, v1.z, v1.w};
    half8 h1, h2;
#pragma unroll
    for (int j = 0; j < 8; j++) {
        h1[j] = (_Float16)f[j];
        h2[j] = (_Float16)((f[j] - (float)h1[j]) * 2048.0f);
    }
    *(half8*)(base + off) = h1;
    *(half8*)(base + ABUF + off) = h2;
}

__launch_bounds__(256, 2)
__global__ void moe_fused_kernel(const float* __restrict__ A,
                                 const _Float16* __restrict__ Bp,
                                 float* __restrict__ out,
                                 float* __restrict__ mece) {
    __shared__ __align__(16) unsigned char smem[2 * BUFSZ];
    __shared__ float tmax[MT], tscale[MT];
    float* LG = (float*)smem;            // overlay: logits [NE][LSTRIDE] after main loop
    const int tid  = threadIdx.x;
    const int wave = tid >> 6;
    const int lane = tid & 63;
    const int quad = lane >> 4;
    const int lrow = lane & 15;
    const int tok0 = blockIdx.x * MT;

    const int srow = tid >> 3;
    const int schunk = tid & 7;
    const float* aptr = A + (size_t)(tok0 + srow) * DM + schunk * 8;
    const unsigned swoff = schunk * CSTRIDE + srow * 16;
    const unsigned aroff = quad * CSTRIDE + lrow * 16;

    const char* bB = (const char*)Bp + (wave * 2) * 2048 + lane * 16;

    floatx4 accm[2][2], accc[2][2];
#pragma unroll
    for (int r = 0; r < 2; r++)
#pragma unroll
        for (int c = 0; c < 2; c++) {
            accm[r][c] = (floatx4){0.f, 0.f, 0.f, 0.f};
            accc[r][c] = (floatx4){0.f, 0.f, 0.f, 0.f};
        }

    {
        float4 v0 = *(const float4*)aptr;
        float4 v1 = *(const float4*)(aptr + 4);
        stage_write(smem, swoff, v0, v1);
    }
    __syncthreads();

    for (int it = 0; it < NITER; ++it) {
        float4 n0, n1;
        if (it < NITER - 1) {
            const float* p = aptr + (it + 1) * BK;
            n0 = *(const float4*)p;
            n1 = *(const float4*)(p + 4);
        }
        unsigned char* cb = smem + (it & 1) * BUFSZ;
        const char* bit = bB + (size_t)it * 32768;

#pragma unroll
        for (int ks = 0; ks < 2; ++ks) {
            half8 b1f[2], b2f[2], a1[2], a2[2];
#pragma unroll
            for (int c = 0; c < 2; c++) {
                b1f[c] = *(const half8*)(bit + ks * 16384 + c * 2048);
                b2f[c] = *(const half8*)(bit + ks * 16384 + c * 2048 + 1024);
            }
#pragma unroll
            for (int r = 0; r < 2; r++) {
                a1[r] = *(const half8*)(cb + ks * 2112 + r * 256 + aroff);
                a2[r] = *(const half8*)(cb + ABUF + ks * 2112 + r * 256 + aroff);
            }
#pragma unroll
            for (int r = 0; r < 2; r++)
#pragma unroll
                for (int c = 0; c < 2; c++) {
                    accm[r][c] = __builtin_amdgcn_mfma_f32_16x16x32_f16(a1[r], b1f[c], accm[r][c], 0, 0, 0);
                    accc[r][c] = __builtin_amdgcn_mfma_f32_16x16x32_f16(a1[r], b2f[c], accc[r][c], 0, 0, 0);
                    accc[r][c] = __builtin_amdgcn_mfma_f32_16x16x32_f16(a2[r], b1f[c], accc[r][c], 0, 0, 0);
                }
        }
        if (it < NITER - 1)
            stage_write(smem + ((it + 1) & 1) * BUFSZ, swoff, n0, n1);
        __syncthreads();
    }
    // main loop done; staging LDS is dead (loop-end barrier passed by all waves).

    // ---- write full 32x128 logit tile to LDS, token-minor, stride 33 (<=2-way banks) ----
#pragma unroll
    for (int r = 0; r < 2; r++)
#pragma unroll
        for (int c = 0; c < 2; c++) {
            const int e  = wave * 32 + c * 16 + lrow;
            const int tt = r * 16 + quad * 4;
#pragma unroll
            for (int g = 0; g < 4; g++)
                LG[e * LSTRIDE + tt + g] = accm[r][c][g] + accc[r][c][g] * (1.0f / 2048.0f);
        }
    __syncthreads();

    // ---- per-token top-2 + gate softmax (32 threads, serial scan over 128 experts) ----
    if (tid < MT) {
        const int t = tid;
        float m1 = -1e30f, m2 = -1e30f;
        int i1 = 0, i2 = 0;
        for (int e = 0; e < NE; e++) {
            float v = LG[e * LSTRIDE + t];
            if (v > m1) { m2 = m1; i2 = i1; m1 = v; i1 = e; }
            else if (v > m2) { m2 = v; i2 = e; }
        }
        float s = 0.f;
        for (int e = 0; e < NE; e++)
            s += __expf((LG[e * LSTRIDE + t] - m1) * (1.0f / TEMP));
        tmax[t] = m1;
        tscale[t] = 1.0f / s;

        const int tg = tok0 + t;
        out[tg * 2 + 0] = (float)i1;
        out[tg * 2 + 1] = (float)i2;
        float d = __expf(m2 - m1);
        float g1 = 1.0f / (1.0f + d);
        out[2 * NTOK + tg * 2 + 0] = g1;
        out[2 * NTOK + tg * 2 + 1] = d * g1;

        atomicAdd(&mece[NE + i1], 1.0f);          // ce count
    }
    __syncthreads();

    // ---- per-expert me partial (128 threads), accumulate globally ----
    if (tid < NE) {
        const int e = tid;
        float s = 0.f;
#pragma unroll
        for (int t = 0; t < MT; t++)
            s += __expf((LG[e * LSTRIDE + t] - tmax[t]) * (1.0f / TEMP)) * tscale[t];
        atomicAdd(&mece[e], s);
    }
}

// ---------------- finalize: loss from me/ce (256 floats) ----------------
__global__ void finalize_kernel(const float* __restrict__ mece, float* __restrict__ out) {
    __shared__ float w2[2];
    const int tid = threadIdx.x;   // 128
    float v = mece[tid] * mece[NE + tid] * ((float)NE / (float)NTOK);
#pragma unroll
    for (int off = 32; off; off >>= 1) v += __shfl_down(v, off);
    if ((tid & 63) == 0) w2[tid >> 6] = v;
    __syncthreads();
    if (tid == 0) out[4 * NTOK] = (w2[0] + w2[1]) / (float)NTOK;
}

extern "C" void kernel_launch(void* const* d_in, const int* in_sizes, int n_in,
                              void* d_out, int out_size, void* d_ws, size_t ws_size,
                              hipStream_t stream) {
    (void)in_sizes; (void)n_in; (void)out_size; (void)ws_size;
    const float* inp = (const float*)d_in[0];
    const float* wg  = (const float*)d_in[1];
    float* out = (float*)d_out;

    _Float16* Bp = (_Float16*)d_ws;                          // 2 MB packed B
    float* mece  = (float*)((char*)d_ws + (2u << 20));       // 256 floats: me[128], ce[128]

    hipMemsetAsync(mece, 0, 2 * NE * sizeof(float), stream);
    pack_b_kernel<<<256, 256, 0, stream>>>(wg, Bp);
    moe_fused_kernel<<<NBLK, 256, 0, stream>>>(inp, Bp, out, mece);
    finalize_kernel<<<1, NE, 0, stream>>>(mece, out);
}